// Round 1
// 358.522 us; speedup vs baseline: 1.0152x; 1.0152x over previous
//
#include <hip/hip_runtime.h>
#include <hip/hip_bf16.h>

typedef __hip_bfloat16 bf16;
typedef __attribute__((ext_vector_type(8))) short short8;
typedef __attribute__((ext_vector_type(4))) float f32x4;

#define B_    8192
#define C_    64
#define NTOT  524288            // B_*C_
#define OUT_W_OFF    67108864   // B_*B_
#define OUT_DATA_OFF (OUT_W_OFF + NTOT)
#define OUT_XN_OFF   (OUT_DATA_OFF + NTOT)

// ---------------- Kernel 1: global sum / sumsq over data = concat(pred, imfs) ----
__global__ __launch_bounds__(256) void reduce_kernel(const float* __restrict__ pred,
                                                     const float* __restrict__ imfs,
                                                     float* __restrict__ sums) {
    float s = 0.f, s2 = 0.f;
    int tid = blockIdx.x * blockDim.x + threadIdx.x;
    int stride = gridDim.x * blockDim.x;
    const f32x4* p4 = (const f32x4*)pred;
    const f32x4* i4 = (const f32x4*)imfs;
    for (int i = tid; i < B_ / 4; i += stride) {
        f32x4 v = p4[i];
        s += v.x + v.y + v.z + v.w;
        s2 += v.x * v.x + v.y * v.y + v.z * v.z + v.w * v.w;
    }
    for (int i = tid; i < (B_ * (C_ - 1)) / 4; i += stride) {
        f32x4 v = i4[i];
        s += v.x + v.y + v.z + v.w;
        s2 += v.x * v.x + v.y * v.y + v.z * v.z + v.w * v.w;
    }
    #pragma unroll
    for (int off = 32; off > 0; off >>= 1) {
        s  += __shfl_down(s,  off, 64);
        s2 += __shfl_down(s2, off, 64);
    }
    __shared__ float ls[4], ls2[4];
    int wv = threadIdx.x >> 6, ln = threadIdx.x & 63;
    if (ln == 0) { ls[wv] = s; ls2[wv] = s2; }
    __syncthreads();
    if (threadIdx.x == 0) {
        float a = 0.f, b = 0.f;
        for (int i = 0; i < 4; i++) { a += ls[i]; b += ls2[i]; }
        atomicAdd(&sums[0], a);
        atomicAdd(&sums[1], b);
    }
}

// ---------------- Kernel 2: per-row pipeline, ONE WAVE PER ROW, no barriers ------
__global__ __launch_bounds__(256) void rows_kernel(
    const float* __restrict__ pred, const float* __restrict__ imfs,
    const float* __restrict__ rev_w, const float* __restrict__ rev_b,
    const float* __restrict__ ca_w1, const float* __restrict__ ca_b1,
    const float* __restrict__ ca_w2, const float* __restrict__ ca_b2,
    const float* __restrict__ conv1_w, const float* __restrict__ conv1_b,
    const float* __restrict__ bn1_g, const float* __restrict__ bn1_b,
    const float* __restrict__ bn1_m, const float* __restrict__ bn1_v,
    const float* __restrict__ conv2_w, const float* __restrict__ conv2_b,
    const float* __restrict__ bn2_g, const float* __restrict__ bn2_b,
    const float* __restrict__ bn2_m, const float* __restrict__ bn2_v,
    const float* __restrict__ sums,
    float* __restrict__ out_w, float* __restrict__ out_data,
    float* __restrict__ out_xn,
    bf16* __restrict__ dhi, bf16* __restrict__ whi) {

    // weight tiles (stride-65/17 padding -> only free 2-way bank conflicts)
    __shared__ float w1s[16 * 65];   // ca_w1[j][c]  at j*65+c
    __shared__ float w2s[64 * 17];   // ca_w2[c][j]  at c*17+j
    __shared__ float c1s[16 * 65];   // conv1 center tap [j][c]
    __shared__ float c2s[64 * 17];   // conv2 center tap [c][j]
    __shared__ float xnb[4][64];     // per-wave row buffer (wave-private)
    __shared__ float h1b[4][16];     // per-wave hidden buffer (wave-private)

    for (int i = threadIdx.x; i < 1024; i += 256) {
        int j = i >> 6, c = i & 63;
        w1s[j * 65 + c] = ca_w1[i];
        c1s[j * 65 + c] = conv1_w[i * 7 + 3];
    }
    for (int i = threadIdx.x; i < 1024; i += 256) {
        int c = i >> 4, j = i & 15;
        w2s[c * 17 + j] = ca_w2[i];
        c2s[c * 17 + j] = conv2_w[i * 7 + 3];
    }
    __syncthreads();

    const int c   = threadIdx.x & 63;   // channel owned by this lane
    const int wv  = threadIdx.x >> 6;
    const int jj  = c & 15;             // hidden index for this lane's partial
    const int q16 = (c >> 4) * 16;      // k-chunk this lane sums

    // hoisted per-lane params
    const float revw = rev_w[c], revb = rev_b[c];
    const float cab2 = ca_b2[c], c2b = conv2_b[c];
    const float bn2s = bn2_g[c] * rsqrtf(bn2_v[c] + 1e-5f);
    const float bn2h = bn2_b[c] - bn2_m[c] * bn2s;
    const float cab1 = ca_b1[jj], c1b = conv1_b[jj];
    const float bn1s = bn1_g[jj] * rsqrtf(bn1_v[jj] + 1e-5f);
    const float bn1h = bn1_b[jj] - bn1_m[jj] * bn1s;

    const float inv_n = 1.0f / (float)NTOT;
    const float mu   = sums[0] * inv_n;
    const float var  = sums[1] * inv_n - mu * mu;
    const float stdv = sqrtf(var + 1e-5f);
    const float istd = 1.0f / stdv;

    const int gw = blockIdx.x * 4 + wv;     // global wave id, 2048 total
    for (int row = gw; row < B_; row += 2048) {
        float d = (c == 0) ? pred[row] : imfs[row * 63 + c - 1];
        out_data[row * 64 + c] = d;
        dhi[row * 64 + c] = __float2bfloat16(d);
        float xn = (d - mu) * istd * revw + revb;
        out_xn[row * 64 + c] = xn;
        xnb[wv][c] = xn;                       // intra-wave LDS: in-order, no barrier
        __builtin_amdgcn_wave_barrier();
        // layer 1 (64->16): lane computes partial for output jj over chunk q16
        float p1 = 0.f;
        #pragma unroll
        for (int i = 0; i < 16; i++) p1 += w1s[jj * 65 + q16 + i] * xnb[wv][q16 + i];
        p1 += __shfl_xor(p1, 16, 64);
        p1 += __shfl_xor(p1, 32, 64);
        float y = fmaxf(p1 + cab1, 0.f);
        if (c < 16) h1b[wv][c] = y;
        __builtin_amdgcn_wave_barrier();
        // layer 2 (16->64)
        float att = cab2;
        #pragma unroll
        for (int j = 0; j < 16; j++) att += w2s[c * 17 + j] * h1b[wv][j];
        float x = xn * att;
        xnb[wv][c] = x;
        __builtin_amdgcn_wave_barrier();
        // conv1 tap (64->16) + bn1 + relu
        float p2 = 0.f;
        #pragma unroll
        for (int i = 0; i < 16; i++) p2 += c1s[jj * 65 + q16 + i] * xnb[wv][q16 + i];
        p2 += __shfl_xor(p2, 16, 64);
        p2 += __shfl_xor(p2, 32, 64);
        float t = fmaxf((p2 + c1b) * bn1s + bn1h, 0.f);
        if (c < 16) h1b[wv][c] = t;
        __builtin_amdgcn_wave_barrier();
        // conv2 tap (16->64) + bn2
        float v = c2b;
        #pragma unroll
        for (int j = 0; j < 16; j++) v += c2s[c * 17 + j] * h1b[wv][j];
        v = v * bn2s + bn2h;
        float sg = 1.0f / (1.0f + __expf(-v));
        float ov = x * sg;
        float wval = (ov - revb) / (revw + 1e-10f) * stdv + mu;
        out_w[row * 64 + c] = wval;
        whi[row * 64 + c] = __float2bfloat16(wval);
        __builtin_amdgcn_wave_barrier();
    }
}

// ---------------- Kernel 3: recon = data @ w^T  (8192x8192, K=64) ---------------
// Operand-swapped streaming GEMM: D = mfma(whi_frag, dhi_frag) puts each lane's
// 4 acc regs on 4 CONSECUTIVE output columns of ONE output row
// (row = b0 + (lane&15), cols = h0 + t*16 + (lane>>4)*4 + r), so the epilogue is
// a single f32x4 nontemporal store per subtile: no LDS tile, no __syncthreads,
// no post-barrier store burst. Every wave streams stores for its whole lifetime.
// 8192 waves (2048 blocks): wave w -> rows [16*(w>>4), +16), cols [512*(w&15), +512).
__global__ __launch_bounds__(256, 4) void gemm_kernel(
    const bf16* __restrict__ dhi, const bf16* __restrict__ whi,
    float* __restrict__ out) {

    const int wid  = (blockIdx.x << 2) + (threadIdx.x >> 6);   // 0..8191
    const int lane = threadIdx.x & 63;
    const int m    = lane & 15;
    const int q    = lane >> 4;

    const int b0 = (wid >> 4) * 16;     // output-row group base
    const int h0 = (wid & 15) * 512;    // output-col chunk base

    const short* dptr = (const short*)dhi;
    const short* wptr = (const short*)whi;

    // B-operand fragments (data rows -> output rows), loaded once per wave
    short8 d0 = *(const short8*)(dptr + (b0 + m) * 64 + q * 8);
    short8 d1 = *(const short8*)(dptr + (b0 + m) * 64 + q * 8 + 32);

    float* orow = out + (long)(b0 + m) * B_ + h0 + q * 4;

    #pragma unroll 4
    for (int t = 0; t < 32; t++) {
        const int h = h0 + t * 16 + m;  // A-operand rows (w rows -> output cols)
        short8 a0 = *(const short8*)(wptr + h * 64 + q * 8);
        short8 a1 = *(const short8*)(wptr + h * 64 + q * 8 + 32);
        f32x4 acc = {0.f, 0.f, 0.f, 0.f};
        acc = __builtin_amdgcn_mfma_f32_16x16x32_bf16(a0, d0, acc, 0, 0, 0);
        acc = __builtin_amdgcn_mfma_f32_16x16x32_bf16(a1, d1, acc, 0, 0, 0);
        // D layout: col(lane&15)=data row m, row(q*4+r)=w row -> consecutive cols
        __builtin_nontemporal_store(acc, (f32x4*)(orow + t * 16));
    }
}

extern "C" void kernel_launch(void* const* d_in, const int* in_sizes, int n_in,
                              void* d_out, int out_size, void* d_ws, size_t ws_size,
                              hipStream_t stream) {
    const float* pred    = (const float*)d_in[0];
    const float* imfs    = (const float*)d_in[1];
    const float* rev_w   = (const float*)d_in[2];
    const float* rev_b   = (const float*)d_in[3];
    const float* ca_w1   = (const float*)d_in[4];
    const float* ca_b1   = (const float*)d_in[5];
    const float* ca_w2   = (const float*)d_in[6];
    const float* ca_b2   = (const float*)d_in[7];
    const float* conv1_w = (const float*)d_in[8];
    const float* conv1_b = (const float*)d_in[9];
    const float* bn1_g   = (const float*)d_in[10];
    const float* bn1_b   = (const float*)d_in[11];
    const float* bn1_m   = (const float*)d_in[12];
    const float* bn1_v   = (const float*)d_in[13];
    const float* conv2_w = (const float*)d_in[14];
    const float* conv2_b = (const float*)d_in[15];
    const float* bn2_g   = (const float*)d_in[16];
    const float* bn2_b   = (const float*)d_in[17];
    const float* bn2_m   = (const float*)d_in[18];
    const float* bn2_v   = (const float*)d_in[19];

    float* out  = (float*)d_out;
    float* sums = (float*)d_ws;
    bf16*  dhi  = (bf16*)((char*)d_ws + 16);
    bf16*  whi  = dhi + NTOT;

    hipMemsetAsync(d_ws, 0, 16, stream);
    reduce_kernel<<<256, 256, 0, stream>>>(pred, imfs, sums);
    rows_kernel<<<512, 256, 0, stream>>>(pred, imfs, rev_w, rev_b, ca_w1, ca_b1,
                                         ca_w2, ca_b2, conv1_w, conv1_b,
                                         bn1_g, bn1_b, bn1_m, bn1_v,
                                         conv2_w, conv2_b, bn2_g, bn2_b, bn2_m, bn2_v,
                                         sums,
                                         out + OUT_W_OFF, out + OUT_DATA_OFF,
                                         out + OUT_XN_OFF, dhi, whi);
    gemm_kernel<<<2048, 256, 0, stream>>>(dhi, whi, out);
}

// Round 2
// 352.535 us; speedup vs baseline: 1.0324x; 1.0170x over previous
//
#include <hip/hip_runtime.h>
#include <hip/hip_bf16.h>

typedef __hip_bfloat16 bf16;
typedef __attribute__((ext_vector_type(8))) short short8;
typedef __attribute__((ext_vector_type(4))) float f32x4;

#define B_    8192
#define C_    64
#define NTOT  524288            // B_*C_
#define OUT_W_OFF    67108864   // B_*B_
#define OUT_DATA_OFF (OUT_W_OFF + NTOT)
#define OUT_XN_OFF   (OUT_DATA_OFF + NTOT)
#define NRED  256               // reduce grid: must match partials layout

// ---------------- Kernel 1: per-block partial sum/sumsq (NO atomics, NO memset) --
// partials[2*b] = block-sum, partials[2*b+1] = block-sumsq. Fully overwritten
// every launch -> idempotent under harness re-runs, needs no zeroing dispatch.
__global__ __launch_bounds__(256) void reduce_kernel(const float* __restrict__ pred,
                                                     const float* __restrict__ imfs,
                                                     float* __restrict__ partials) {
    float s = 0.f, s2 = 0.f;
    int tid = blockIdx.x * blockDim.x + threadIdx.x;
    int stride = gridDim.x * blockDim.x;
    const f32x4* p4 = (const f32x4*)pred;
    const f32x4* i4 = (const f32x4*)imfs;
    for (int i = tid; i < B_ / 4; i += stride) {
        f32x4 v = p4[i];
        s += v.x + v.y + v.z + v.w;
        s2 += v.x * v.x + v.y * v.y + v.z * v.z + v.w * v.w;
    }
    for (int i = tid; i < (B_ * (C_ - 1)) / 4; i += stride) {
        f32x4 v = i4[i];
        s += v.x + v.y + v.z + v.w;
        s2 += v.x * v.x + v.y * v.y + v.z * v.z + v.w * v.w;
    }
    #pragma unroll
    for (int off = 32; off > 0; off >>= 1) {
        s  += __shfl_down(s,  off, 64);
        s2 += __shfl_down(s2, off, 64);
    }
    __shared__ float ls[4], ls2[4];
    int wv = threadIdx.x >> 6, ln = threadIdx.x & 63;
    if (ln == 0) { ls[wv] = s; ls2[wv] = s2; }
    __syncthreads();
    if (threadIdx.x == 0) {
        float a = 0.f, b = 0.f;
        for (int i = 0; i < 4; i++) { a += ls[i]; b += ls2[i]; }
        partials[2 * blockIdx.x]     = a;
        partials[2 * blockIdx.x + 1] = b;
    }
}

// ---------------- Kernel 2: per-row pipeline, ONE WAVE PER ROW, no barriers ------
__global__ __launch_bounds__(256) void rows_kernel(
    const float* __restrict__ pred, const float* __restrict__ imfs,
    const float* __restrict__ rev_w, const float* __restrict__ rev_b,
    const float* __restrict__ ca_w1, const float* __restrict__ ca_b1,
    const float* __restrict__ ca_w2, const float* __restrict__ ca_b2,
    const float* __restrict__ conv1_w, const float* __restrict__ conv1_b,
    const float* __restrict__ bn1_g, const float* __restrict__ bn1_b,
    const float* __restrict__ bn1_m, const float* __restrict__ bn1_v,
    const float* __restrict__ conv2_w, const float* __restrict__ conv2_b,
    const float* __restrict__ bn2_g, const float* __restrict__ bn2_b,
    const float* __restrict__ bn2_m, const float* __restrict__ bn2_v,
    const float* __restrict__ partials,
    float* __restrict__ out_w, float* __restrict__ out_data,
    float* __restrict__ out_xn,
    bf16* __restrict__ dhi, bf16* __restrict__ whi) {

    // weight tiles (stride-65/17 padding -> only free 2-way bank conflicts)
    __shared__ float w1s[16 * 65];   // ca_w1[j][c]  at j*65+c
    __shared__ float w2s[64 * 17];   // ca_w2[c][j]  at c*17+j
    __shared__ float c1s[16 * 65];   // conv1 center tap [j][c]
    __shared__ float c2s[64 * 17];   // conv2 center tap [c][j]
    __shared__ float xnb[4][64];     // per-wave row buffer (wave-private)
    __shared__ float h1b[4][16];     // per-wave hidden buffer (wave-private)

    for (int i = threadIdx.x; i < 1024; i += 256) {
        int j = i >> 6, c = i & 63;
        w1s[j * 65 + c] = ca_w1[i];
        c1s[j * 65 + c] = conv1_w[i * 7 + 3];
    }
    for (int i = threadIdx.x; i < 1024; i += 256) {
        int c = i >> 4, j = i & 15;
        w2s[c * 17 + j] = ca_w2[i];
        c2s[c * 17 + j] = conv2_w[i * 7 + 3];
    }
    __syncthreads();

    const int c   = threadIdx.x & 63;   // channel owned by this lane
    const int wv  = threadIdx.x >> 6;
    const int jj  = c & 15;             // hidden index for this lane's partial
    const int q16 = (c >> 4) * 16;      // k-chunk this lane sums

    // prologue: self-reduce the 256 {s,s2} partials (512 floats) in-wave.
    // Each lane reads 2 f32x4 (covers 2 partial-pairs each), xor-reduce 6 steps.
    {
        const f32x4* pp = (const f32x4*)partials;   // 128 vectors
        f32x4 v0 = pp[c];
        f32x4 v1 = pp[64 + c];
        float s  = v0.x + v0.z + v1.x + v1.z;
        float s2 = v0.y + v0.w + v1.y + v1.w;
        #pragma unroll
        for (int off = 32; off > 0; off >>= 1) {
            s  += __shfl_xor(s,  off, 64);
            s2 += __shfl_xor(s2, off, 64);
        }
        xnb[wv][0] = s;      // stash per-wave (keeps the values uniform-register)
        xnb[wv][1] = s2;
    }
    __builtin_amdgcn_wave_barrier();
    const float inv_n = 1.0f / (float)NTOT;
    const float mu   = xnb[wv][0] * inv_n;
    const float var  = xnb[wv][1] * inv_n - mu * mu;
    const float stdv = sqrtf(var + 1e-5f);
    const float istd = 1.0f / stdv;
    __builtin_amdgcn_wave_barrier();

    // hoisted per-lane params
    const float revw = rev_w[c], revb = rev_b[c];
    const float cab2 = ca_b2[c], c2b = conv2_b[c];
    const float bn2s = bn2_g[c] * rsqrtf(bn2_v[c] + 1e-5f);
    const float bn2h = bn2_b[c] - bn2_m[c] * bn2s;
    const float cab1 = ca_b1[jj], c1b = conv1_b[jj];
    const float bn1s = bn1_g[jj] * rsqrtf(bn1_v[jj] + 1e-5f);
    const float bn1h = bn1_b[jj] - bn1_m[jj] * bn1s;

    const int gw = blockIdx.x * 4 + wv;     // global wave id, 2048 total
    for (int row = gw; row < B_; row += 2048) {
        float d = (c == 0) ? pred[row] : imfs[row * 63 + c - 1];
        out_data[row * 64 + c] = d;
        dhi[row * 64 + c] = __float2bfloat16(d);
        float xn = (d - mu) * istd * revw + revb;
        out_xn[row * 64 + c] = xn;
        xnb[wv][c] = xn;                       // intra-wave LDS: in-order, no barrier
        __builtin_amdgcn_wave_barrier();
        // layer 1 (64->16): lane computes partial for output jj over chunk q16
        float p1 = 0.f;
        #pragma unroll
        for (int i = 0; i < 16; i++) p1 += w1s[jj * 65 + q16 + i] * xnb[wv][q16 + i];
        p1 += __shfl_xor(p1, 16, 64);
        p1 += __shfl_xor(p1, 32, 64);
        float y = fmaxf(p1 + cab1, 0.f);
        if (c < 16) h1b[wv][c] = y;
        __builtin_amdgcn_wave_barrier();
        // layer 2 (16->64)
        float att = cab2;
        #pragma unroll
        for (int j = 0; j < 16; j++) att += w2s[c * 17 + j] * h1b[wv][j];
        float x = xn * att;
        xnb[wv][c] = x;
        __builtin_amdgcn_wave_barrier();
        // conv1 tap (64->16) + bn1 + relu
        float p2 = 0.f;
        #pragma unroll
        for (int i = 0; i < 16; i++) p2 += c1s[jj * 65 + q16 + i] * xnb[wv][q16 + i];
        p2 += __shfl_xor(p2, 16, 64);
        p2 += __shfl_xor(p2, 32, 64);
        float t = fmaxf((p2 + c1b) * bn1s + bn1h, 0.f);
        if (c < 16) h1b[wv][c] = t;
        __builtin_amdgcn_wave_barrier();
        // conv2 tap (16->64) + bn2
        float v = c2b;
        #pragma unroll
        for (int j = 0; j < 16; j++) v += c2s[c * 17 + j] * h1b[wv][j];
        v = v * bn2s + bn2h;
        float sg = 1.0f / (1.0f + __expf(-v));
        float ov = x * sg;
        float wval = (ov - revb) / (revw + 1e-10f) * stdv + mu;
        out_w[row * 64 + c] = wval;
        whi[row * 64 + c] = __float2bfloat16(wval);
        __builtin_amdgcn_wave_barrier();
    }
}

// ---------------- Kernel 3: recon = data @ w^T  (8192x8192, K=64) ---------------
// Operand-swapped streaming GEMM: D = mfma(whi_frag, dhi_frag) puts each lane's
// 4 acc regs on 4 CONSECUTIVE output columns of ONE output row, so the epilogue
// is a single f32x4 nontemporal store per subtile: no LDS, no __syncthreads.
__global__ __launch_bounds__(256, 4) void gemm_kernel(
    const bf16* __restrict__ dhi, const bf16* __restrict__ whi,
    float* __restrict__ out) {

    const int wid  = (blockIdx.x << 2) + (threadIdx.x >> 6);   // 0..8191
    const int lane = threadIdx.x & 63;
    const int m    = lane & 15;
    const int q    = lane >> 4;

    const int b0 = (wid >> 4) * 16;     // output-row group base
    const int h0 = (wid & 15) * 512;    // output-col chunk base

    const short* dptr = (const short*)dhi;
    const short* wptr = (const short*)whi;

    // B-operand fragments (data rows -> output rows), loaded once per wave
    short8 d0 = *(const short8*)(dptr + (b0 + m) * 64 + q * 8);
    short8 d1 = *(const short8*)(dptr + (b0 + m) * 64 + q * 8 + 32);

    float* orow = out + (long)(b0 + m) * B_ + h0 + q * 4;

    #pragma unroll 4
    for (int t = 0; t < 32; t++) {
        const int h = h0 + t * 16 + m;  // A-operand rows (w rows -> output cols)
        short8 a0 = *(const short8*)(wptr + h * 64 + q * 8);
        short8 a1 = *(const short8*)(wptr + h * 64 + q * 8 + 32);
        f32x4 acc = {0.f, 0.f, 0.f, 0.f};
        acc = __builtin_amdgcn_mfma_f32_16x16x32_bf16(a0, d0, acc, 0, 0, 0);
        acc = __builtin_amdgcn_mfma_f32_16x16x32_bf16(a1, d1, acc, 0, 0, 0);
        // D layout: col(lane&15)=data row m, row(q*4+r)=w row -> consecutive cols
        __builtin_nontemporal_store(acc, (f32x4*)(orow + t * 16));
    }
}

extern "C" void kernel_launch(void* const* d_in, const int* in_sizes, int n_in,
                              void* d_out, int out_size, void* d_ws, size_t ws_size,
                              hipStream_t stream) {
    const float* pred    = (const float*)d_in[0];
    const float* imfs    = (const float*)d_in[1];
    const float* rev_w   = (const float*)d_in[2];
    const float* rev_b   = (const float*)d_in[3];
    const float* ca_w1   = (const float*)d_in[4];
    const float* ca_b1   = (const float*)d_in[5];
    const float* ca_w2   = (const float*)d_in[6];
    const float* ca_b2   = (const float*)d_in[7];
    const float* conv1_w = (const float*)d_in[8];
    const float* conv1_b = (const float*)d_in[9];
    const float* bn1_g   = (const float*)d_in[10];
    const float* bn1_b   = (const float*)d_in[11];
    const float* bn1_m   = (const float*)d_in[12];
    const float* bn1_v   = (const float*)d_in[13];
    const float* conv2_w = (const float*)d_in[14];
    const float* conv2_b = (const float*)d_in[15];
    const float* bn2_g   = (const float*)d_in[16];
    const float* bn2_b   = (const float*)d_in[17];
    const float* bn2_m   = (const float*)d_in[18];
    const float* bn2_v   = (const float*)d_in[19];

    float* out      = (float*)d_out;
    float* partials = (float*)d_ws;                    // 256 blocks x {s,s2} = 2KB
    bf16*  dhi      = (bf16*)((char*)d_ws + 2048);
    bf16*  whi      = dhi + NTOT;

    reduce_kernel<<<NRED, 256, 0, stream>>>(pred, imfs, partials);
    rows_kernel<<<512, 256, 0, stream>>>(pred, imfs, rev_w, rev_b, ca_w1, ca_b1,
                                         ca_w2, ca_b2, conv1_w, conv1_b,
                                         bn1_g, bn1_b, bn1_m, bn1_v,
                                         conv2_w, conv2_b, bn2_g, bn2_b, bn2_m, bn2_v,
                                         partials,
                                         out + OUT_W_OFF, out + OUT_DATA_OFF,
                                         out + OUT_XN_OFF, dhi, whi);
    gemm_kernel<<<2048, 256, 0, stream>>>(dhi, whi, out);
}